// Round 10
// baseline (74.344 us; speedup 1.0000x reference)
//
#include <hip/hip_runtime.h>
#include <stdint.h>

#define D_DIM 1024
#define N_DIM 65536
#define Q_DIM 2048
#define K_DIM 3

#define NBLK  256            // one block per CU
#define TPB   1024           // 16 waves
#define MACW  32             // cols per macro (compute granularity)
#define NMAC  8              // macros per block -> 256 cols
#define NQT   32             // total stage-quarters (NMAC * 4)
#define QROWS 256            // quarter = 256 rows x 128 B = 32 KB

// LDS map (dynamic): ring 4 x 32 KB + fp8 table 32 KB = exactly 160 KiB
#define RING_OFF  0
#define TAB_OFF   131072     // fp8 table [1024 rows][32 cols] = 32768 B, granule-swizzled
#define LDS_TOTAL 163840

#define VMCNT6() asm volatile("s_waitcnt vmcnt(6)" ::: "memory")
#define VMCNT4() asm volatile("s_waitcnt vmcnt(4)" ::: "memory")
#define VMCNT2() asm volatile("s_waitcnt vmcnt(2)" ::: "memory")
#define VMCNT0() asm volatile("s_waitcnt vmcnt(0)" ::: "memory")
#define LGKM0()  asm volatile("s_waitcnt lgkmcnt(0)" ::: "memory")
#define SCHED0() __builtin_amdgcn_sched_barrier(0)
#define SBAR()   __builtin_amdgcn_s_barrier()

typedef const __attribute__((address_space(1))) uint32_t  glb_u32;
typedef __attribute__((address_space(3))) uint32_t        lds_u32;

// ---- manual fp8 (e4m3, positive-normal-only) codec; values pre-scaled x64 ----
// encode: RNE at bit 20, rebias 127->7.  valid for x in [2^-6, 448) -- our
// probs*64 are in [0.54, 21.1].
__device__ __forceinline__ uint32_t f2fp8(float x) {
    uint32_t u = __float_as_uint(x);
    u += 0x7FFFFu + ((u >> 20) & 1u);
    return (u >> 20) - 960u;           // (120 << 3)
}
// decode: exact
#define DEC(b) __uint_as_float(((b) + 960u) << 20)

// DMA one quarter (256 rows x 128 B) into ring slot q&3 (slot == slab s of
// macro q>>2, since NQT slabs/macro == ring size == 4). Wave w stages its OWN
// rows [w*16, w*16+16): 2 insts x (8 rows x full 128-B span), fully linear on
// both sides. Slot regions are wave-local on produce AND consume -> no
// cross-wave LDS hazards, no barriers in the staging loop.
__device__ __forceinline__ void stage_quarter(const float* __restrict__ W, char* smem,
                                              int q, int bid, int w, int l) {
    const int slot = (q & 3) << 15;
    const int col0 = bid * (NMAC * MACW) + (q >> 2) * MACW;    // floats
    const int r0   = (q & 3) * QROWS + w * 16 + (l >> 3);
    const float* g0 = W + ((size_t)r0 << 16) + col0 + (l & 7) * 4;
    const float* g1 = W + ((size_t)(r0 + 8) << 16) + col0 + (l & 7) * 4;
    __builtin_amdgcn_global_load_lds((glb_u32*)g0,
        (lds_u32*)(smem + RING_OFF + slot + w * 2048 + l * 16), 16, 0, 0);
    __builtin_amdgcn_global_load_lds((glb_u32*)g1,
        (lds_u32*)(smem + RING_OFF + slot + w * 2048 + 1024 + l * 16), 16, 0, 0);
}

// compute phase: 2 queries x 4 granules x 8 cols; fp8 table, b64 reads
#define TRIPLE(va, vb, vc, sh, acc)                                                   \
    acc = fmaf(DEC(((va) >> (sh)) & 0xFFu) * DEC(((vb) >> (sh)) & 0xFFu),             \
               DEC(((vc) >> (sh)) & 0xFFu), acc)

#define COMPUTE_PHASE()                                                               \
    _Pragma("unroll")                                                                 \
    for (int g16 = 0; g16 < 4; ++g16) {                                               \
        const int gb = g16 << 3;                                                      \
        _Pragma("unroll")                                                             \
        for (int qq2 = 0; qq2 < 2; ++qq2) {                                           \
            const uint2 va = *(const uint2*)(smem + TAB_OFF + baseb[qq2][0]           \
                                             + (gb ^ swzb[qq2][0]));                  \
            const uint2 vb = *(const uint2*)(smem + TAB_OFF + baseb[qq2][1]           \
                                             + (gb ^ swzb[qq2][1]));                  \
            const uint2 vc = *(const uint2*)(smem + TAB_OFF + baseb[qq2][2]           \
                                             + (gb ^ swzb[qq2][2]));                  \
            float& acc = qq2 ? acc1 : acc0;                                           \
            TRIPLE(va.x, vb.x, vc.x, 0, acc);                                         \
            TRIPLE(va.x, vb.x, vc.x, 8, acc);                                         \
            TRIPLE(va.x, vb.x, vc.x, 16, acc);                                        \
            TRIPLE(va.x, vb.x, vc.x, 24, acc);                                        \
            TRIPLE(va.y, vb.y, vc.y, 0, acc);                                         \
            TRIPLE(va.y, vb.y, vc.y, 8, acc);                                         \
            TRIPLE(va.y, vb.y, vc.y, 16, acc);                                        \
            TRIPLE(va.y, vb.y, vc.y, 24, acc);                                        \
        }                                                                             \
    }

template<bool ATOMIC>
__global__ __launch_bounds__(TPB, 4) void rap_main(const float* __restrict__ W,
                                                   const int* __restrict__ qidx,
                                                   float* __restrict__ outp) {
    extern __shared__ char smem[];
    const int tid = threadIdx.x;
    const int bid = blockIdx.x;
    const int w = tid >> 6, l = tid & 63;

    // ---- per-thread query constants (2 queries/thread) ----
    const int q0 = tid * 2;
    int baseb[2][K_DIM];   // d*32 : byte base of fp8 table row
    int swzb[2][K_DIM];    // ((d>>1)&3)<<3 : granule XOR key in bytes
#pragma unroll
    for (int qq = 0; qq < 2; ++qq) {
#pragma unroll
        for (int k = 0; k < K_DIM; ++k) {
            const int d = qidx[(q0 + qq) * K_DIM + k];
            baseb[qq][k] = d << 5;
            swzb[qq][k]  = ((d >> 1) & 3) << 3;
        }
    }

    // ---- fused-pass mapping: lane -> (col, even/odd row half) ----
    const int c = l & 31;            // macro col 0..31
    const int h = l >> 5;            // 0 = even rows, 1 = odd rows

    float acc0 = 0.f, acc1 = 0.f;

    // drain qidx loads so vmcnt counts only stage DMAs; prefill 3 quarters
    VMCNT0(); SCHED0();
    stage_quarter(W, smem, 0, bid, w, l);
    stage_quarter(W, smem, 1, bid, w, l);
    stage_quarter(W, smem, 2, bid, w, l);

    for (int m = 0; m < NMAC; ++m) {
#pragma unroll
        for (int s = 0; s < 4; ++s) {
            const int q = m * 4 + s;

            // issue 3-ahead BEFORE the gate: steady in-flight = 8 insts/wave.
            // slot (q+3)&3 == slot of q-1, whose wave-local reads retired when
            // last iteration's exps consumed them.
            if (q + 3 < NQT) stage_quarter(W, smem, q + 3, bid, w, l);
            SCHED0();

            // gate: quarter q's 2 insts arrived (FIFO vmcnt); tail tightens
            const int rem = (NQT - 1) - q;
            if (rem >= 3)      { VMCNT6(); }
            else if (rem == 2) { VMCNT4(); }
            else if (rem == 1) { VMCNT2(); }
            else               { VMCNT0(); }
            SCHED0();

            // ---- fused softmax: exp once, shfl denominator, fp8 col-write ----
            {
                const char* p = smem + RING_OFF + ((q & 3) << 15)
                                + (w * 16 + h) * 128 + c * 4;
                float e[8]; float sum = 0.f;
#pragma unroll
                for (int j = 0; j < 8; ++j) {           // rows h, h+2, .., h+14
                    e[j] = __expf(*(const float*)(p + j * 256));
                    sum += e[j];
                }
                sum += __shfl_xor(sum, 32);             // combine even+odd halves
                const float rec64 = __builtin_amdgcn_rcpf(sum) * 64.0f;
                const int rbase = (q & 3) * 256 + w * 16 + h;
#pragma unroll
                for (int j = 0; j < 8; ++j) {
                    const int row = rbase + 2 * j;
                    *(uint8_t*)(smem + TAB_OFF + row * 32
                                + ((((c >> 3) ^ ((row >> 1) & 3))) << 3)
                                + (c & 7)) = (uint8_t)f2fp8(e[j] * rec64);
                }
            }
        }

        LGKM0(); SCHED0(); SBAR(); SCHED0();   // table published

        COMPUTE_PHASE();

        LGKM0(); SCHED0(); SBAR(); SCHED0();   // table consumed -> free for next macro
    }

    // acc carries (64)^3 scaling -> 2^18; final mean also /65536 -> 2^34 total
    if (ATOMIC) {
        atomicAdd(outp + q0,     acc0 * (1.0f / 17179869184.0f));
        atomicAdd(outp + q0 + 1, acc1 * (1.0f / 17179869184.0f));
    } else {
        // transposed partials [q][bid] so the reduce reads contiguously
        outp[(size_t)q0 * NBLK + bid]       = acc0;
        outp[(size_t)(q0 + 1) * NBLK + bid] = acc1;
    }
}

// 256 blocks x 256 threads; each wave reduces 2 queries (256 contiguous f32 each)
__global__ __launch_bounds__(256) void rap_reduce(const float* __restrict__ partials,
                                                  float* __restrict__ outp) {
    const int wv = threadIdx.x >> 6;
    const int l  = threadIdx.x & 63;
    const int qb = blockIdx.x * 8 + wv * 2;
#pragma unroll
    for (int i = 0; i < 2; ++i) {
        const int q = qb + i;
        const float* p = partials + (size_t)q * NBLK;
        float s = p[l] + p[l + 64] + p[l + 128] + p[l + 192];
        s += __shfl_xor(s, 1);
        s += __shfl_xor(s, 2);
        s += __shfl_xor(s, 4);
        s += __shfl_xor(s, 8);
        s += __shfl_xor(s, 16);
        s += __shfl_xor(s, 32);
        if (l == 0) outp[q] = s * (1.0f / 17179869184.0f);   // 2^-34
    }
}

extern "C" void kernel_launch(void* const* d_in, const int* in_sizes, int n_in,
                              void* d_out, int out_size, void* d_ws, size_t ws_size,
                              hipStream_t stream) {
    const float* W    = (const float*)d_in[0];
    const int*   qidx = (const int*)d_in[1];
    float*       outp = (float*)d_out;

    const size_t need = (size_t)Q_DIM * NBLK * sizeof(float);
    if (ws_size >= need) {
        (void)hipFuncSetAttribute((const void*)rap_main<false>,
                                  hipFuncAttributeMaxDynamicSharedMemorySize, LDS_TOTAL);
        float* partials = (float*)d_ws;
        hipLaunchKernelGGL(rap_main<false>, dim3(NBLK), dim3(TPB), LDS_TOTAL, stream,
                           W, qidx, partials);
        hipLaunchKernelGGL(rap_reduce, dim3(Q_DIM / 8), dim3(256), 0, stream,
                           partials, outp);
    } else {
        (void)hipFuncSetAttribute((const void*)rap_main<true>,
                                  hipFuncAttributeMaxDynamicSharedMemorySize, LDS_TOTAL);
        (void)hipMemsetAsync(d_out, 0, Q_DIM * sizeof(float), stream);
        hipLaunchKernelGGL(rap_main<true>, dim3(NBLK), dim3(TPB), LDS_TOTAL, stream,
                           W, qidx, outp);
    }
}

// Round 11
// 66.552 us; speedup vs baseline: 1.1171x; 1.1171x over previous
//
#include <hip/hip_runtime.h>
#include <stdint.h>

#define D_DIM 1024
#define N_DIM 65536
#define Q_DIM 2048
#define K_DIM 3

#define NBLK  256            // one block per CU
#define TPB   1024           // 16 waves
#define MACW  32             // cols per macro (compute granularity)
#define NMAC  8              // macros per block -> 256 cols
#define NQT   32             // total stage-quarters (NMAC * 4)
#define QROWS 256            // quarter = 256 rows x 128 B = 32 KB

// LDS map (dynamic): ring 3 x 32 KB + bf16 table 64 KB = exactly 160 KiB
#define RING_OFF  0
#define TAB_OFF   98304      // bf16 table [1024 rows][32 cols], granule-swizzled
#define LDS_TOTAL 163840

#define VMCNT4() asm volatile("s_waitcnt vmcnt(4)" ::: "memory")
#define VMCNT2() asm volatile("s_waitcnt vmcnt(2)" ::: "memory")
#define VMCNT0() asm volatile("s_waitcnt vmcnt(0)" ::: "memory")
#define LGKM0()  asm volatile("s_waitcnt lgkmcnt(0)" ::: "memory")
#define SCHED0() __builtin_amdgcn_sched_barrier(0)
#define SBAR()   __builtin_amdgcn_s_barrier()

typedef const __attribute__((address_space(1))) uint32_t  glb_u32;
typedef __attribute__((address_space(3))) uint32_t        lds_u32;

// round-to-nearest-even f32 -> bf16 (positive normal probs)
__device__ __forceinline__ uint32_t f2bf(float f) {
    uint32_t u = __float_as_uint(f);
    return (u + 0x7fffu + ((u >> 16) & 1u)) >> 16;
}
__device__ __forceinline__ float blo(uint32_t u) { return __uint_as_float(u << 16); }
__device__ __forceinline__ float bhi(uint32_t u) { return __uint_as_float(u & 0xffff0000u); }

// DMA one quarter (256 rows x 128 B) into ring slot q%3. Wave w stages its
// OWN rows [w*16, w*16+16): 2 insts x (8 rows x full 128-B span), fully
// linear on both sides. Slot regions are wave-local on produce AND consume
// -> no cross-wave LDS hazards, no barriers in the staging loop.
__device__ __forceinline__ void stage_quarter(const float* __restrict__ W, char* smem,
                                              int q, int bid, int w, int l) {
    const int slot = (q % 3) * 32768;
    const int col0 = bid * (NMAC * MACW) + (q >> 2) * MACW;    // floats
    const int r0   = (q & 3) * QROWS + w * 16 + (l >> 3);
    const float* g0 = W + ((size_t)r0 << 16) + col0 + (l & 7) * 4;
    const float* g1 = W + ((size_t)(r0 + 8) << 16) + col0 + (l & 7) * 4;
    __builtin_amdgcn_global_load_lds((glb_u32*)g0,
        (lds_u32*)(smem + RING_OFF + slot + w * 2048 + l * 16), 16, 0, 0);
    __builtin_amdgcn_global_load_lds((glb_u32*)g1,
        (lds_u32*)(smem + RING_OFF + slot + w * 2048 + 1024 + l * 16), 16, 0, 0);
}

// compute phase: 2 queries x 4 granules x 8 cols (verbatim R9 layout)
#define COMPUTE_PHASE()                                                                           \
    _Pragma("unroll")                                                                             \
    for (int g16 = 0; g16 < 4; ++g16) {                                                           \
        const int gb = g16 << 4;                                                                  \
        {                                                                                         \
            const uint4 va = *(const uint4*)(smem + TAB_OFF + baseb[0][0] + (gb ^ swzb[0][0]));   \
            const uint4 vb = *(const uint4*)(smem + TAB_OFF + baseb[0][1] + (gb ^ swzb[0][1]));   \
            const uint4 vc = *(const uint4*)(smem + TAB_OFF + baseb[0][2] + (gb ^ swzb[0][2]));   \
            acc0 = fmaf(blo(va.x) * blo(vb.x), blo(vc.x), acc0);                                  \
            acc0 = fmaf(bhi(va.x) * bhi(vb.x), bhi(vc.x), acc0);                                  \
            acc0 = fmaf(blo(va.y) * blo(vb.y), blo(vc.y), acc0);                                  \
            acc0 = fmaf(bhi(va.y) * bhi(vb.y), bhi(vc.y), acc0);                                  \
            acc0 = fmaf(blo(va.z) * blo(vb.z), blo(vc.z), acc0);                                  \
            acc0 = fmaf(bhi(va.z) * bhi(vb.z), bhi(vc.z), acc0);                                  \
            acc0 = fmaf(blo(va.w) * blo(vb.w), blo(vc.w), acc0);                                  \
            acc0 = fmaf(bhi(va.w) * bhi(vb.w), bhi(vc.w), acc0);                                  \
        }                                                                                         \
        {                                                                                         \
            const uint4 va = *(const uint4*)(smem + TAB_OFF + baseb[1][0] + (gb ^ swzb[1][0]));   \
            const uint4 vb = *(const uint4*)(smem + TAB_OFF + baseb[1][1] + (gb ^ swzb[1][1]));   \
            const uint4 vc = *(const uint4*)(smem + TAB_OFF + baseb[1][2] + (gb ^ swzb[1][2]));   \
            acc1 = fmaf(blo(va.x) * blo(vb.x), blo(vc.x), acc1);                                  \
            acc1 = fmaf(bhi(va.x) * bhi(vb.x), bhi(vc.x), acc1);                                  \
            acc1 = fmaf(blo(va.y) * blo(vb.y), blo(vc.y), acc1);                                  \
            acc1 = fmaf(bhi(va.y) * bhi(vb.y), bhi(vc.y), acc1);                                  \
            acc1 = fmaf(blo(va.z) * blo(vb.z), blo(vc.z), acc1);                                  \
            acc1 = fmaf(bhi(va.z) * bhi(vb.z), bhi(vc.z), acc1);                                  \
            acc1 = fmaf(blo(va.w) * blo(vb.w), blo(vc.w), acc1);                                  \
            acc1 = fmaf(bhi(va.w) * bhi(vb.w), bhi(vc.w), acc1);                                  \
        }                                                                                         \
    }

template<bool ATOMIC>
__global__ __launch_bounds__(TPB, 4) void rap_main(const float* __restrict__ W,
                                                   const int* __restrict__ qidx,
                                                   float* __restrict__ outp) {
    extern __shared__ char smem[];
    const int tid = threadIdx.x;
    const int bid = blockIdx.x;
    const int w = tid >> 6, l = tid & 63;

    // ---- per-thread query constants (2 queries/thread) ----
    const int q0 = tid * 2;
    int baseb[2][K_DIM];   // d*64 : byte base of table row
    int swzb[2][K_DIM];    // ((d>>1)&3)<<4 : granule XOR key in bytes
#pragma unroll
    for (int qq = 0; qq < 2; ++qq) {
#pragma unroll
        for (int k = 0; k < K_DIM; ++k) {
            const int d = qidx[(q0 + qq) * K_DIM + k];
            baseb[qq][k] = d << 6;
            swzb[qq][k]  = ((d >> 1) & 3) << 4;
        }
    }

    // ---- fused-pass mapping: lane -> (col, even/odd row half) ----
    const int c = l & 31;            // macro col 0..31
    const int h = l >> 5;            // 0 = even rows, 1 = odd rows

    float acc0 = 0.f, acc1 = 0.f;

    // drain qidx loads so vmcnt counts only stage DMAs; prefill ring
    VMCNT0(); SCHED0();
    stage_quarter(W, smem, 0, bid, w, l);
    stage_quarter(W, smem, 1, bid, w, l);

    for (int m = 0; m < NMAC; ++m) {
#pragma unroll
        for (int s = 0; s < 4; ++s) {
            const int q = m * 4 + s;

            // issue 2-ahead BEFORE the gate: steady in-flight = 6 insts/wave.
            // slot (q+2)%3 == slot of q-1, whose wave-local reads retired when
            // this wave consumed its exps last iteration.
            if (q + 2 < NQT) stage_quarter(W, smem, q + 2, bid, w, l);
            SCHED0();

            // gate: quarter q's 2 insts arrived (FIFO vmcnt); tail tightens
            const int rem = (NQT - 1) - q;
            if (rem >= 2)      { VMCNT4(); }
            else if (rem == 1) { VMCNT2(); }
            else               { VMCNT0(); }
            SCHED0();

            // ---- fused softmax: exp once, shfl denominator, col-wise u16 write ----
            {
                const char* p = smem + RING_OFF + (q % 3) * 32768
                                + (w * 16 + h) * 128 + c * 4;
                float e[8]; float sum = 0.f;
#pragma unroll
                for (int j = 0; j < 8; ++j) {           // rows h, h+2, .., h+14
                    e[j] = __expf(*(const float*)(p + j * 256));
                    sum += e[j];
                }
                sum += __shfl_xor(sum, 32);             // combine even+odd halves
                const float rec = __builtin_amdgcn_rcpf(sum);
                const int rbase = (q & 3) * 256 + w * 16 + h;
#pragma unroll
                for (int j = 0; j < 8; ++j) {
                    const int row = rbase + 2 * j;
                    const uint32_t bf = f2bf(e[j] * rec);
                    *(uint16_t*)(smem + TAB_OFF + row * 64
                                 + ((((c >> 3) ^ ((row >> 1) & 3))) << 4)
                                 + ((c & 7) << 1)) = (uint16_t)bf;
                }
            }
        }

        LGKM0(); SCHED0(); SBAR(); SCHED0();   // table published

        COMPUTE_PHASE();

        LGKM0(); SCHED0(); SBAR(); SCHED0();   // table consumed -> free for next macro
    }

    if (ATOMIC) {
        atomicAdd(outp + q0,     acc0 * (1.0f / N_DIM));
        atomicAdd(outp + q0 + 1, acc1 * (1.0f / N_DIM));
    } else {
        // transposed partials [q][bid] so the reduce reads contiguously
        outp[(size_t)q0 * NBLK + bid]       = acc0;
        outp[(size_t)(q0 + 1) * NBLK + bid] = acc1;
    }
}

// 256 blocks x 256 threads; each wave reduces 2 queries (256 contiguous f32 each)
__global__ __launch_bounds__(256) void rap_reduce(const float* __restrict__ partials,
                                                  float* __restrict__ outp) {
    const int wv = threadIdx.x >> 6;
    const int l  = threadIdx.x & 63;
    const int qb = blockIdx.x * 8 + wv * 2;
#pragma unroll
    for (int i = 0; i < 2; ++i) {
        const int q = qb + i;
        const float* p = partials + (size_t)q * NBLK;
        float s = p[l] + p[l + 64] + p[l + 128] + p[l + 192];
        s += __shfl_xor(s, 1);
        s += __shfl_xor(s, 2);
        s += __shfl_xor(s, 4);
        s += __shfl_xor(s, 8);
        s += __shfl_xor(s, 16);
        s += __shfl_xor(s, 32);
        if (l == 0) outp[q] = s * (1.0f / N_DIM);
    }
}

extern "C" void kernel_launch(void* const* d_in, const int* in_sizes, int n_in,
                              void* d_out, int out_size, void* d_ws, size_t ws_size,
                              hipStream_t stream) {
    const float* W    = (const float*)d_in[0];
    const int*   qidx = (const int*)d_in[1];
    float*       outp = (float*)d_out;

    const size_t need = (size_t)Q_DIM * NBLK * sizeof(float);
    if (ws_size >= need) {
        (void)hipFuncSetAttribute((const void*)rap_main<false>,
                                  hipFuncAttributeMaxDynamicSharedMemorySize, LDS_TOTAL);
        float* partials = (float*)d_ws;
        hipLaunchKernelGGL(rap_main<false>, dim3(NBLK), dim3(TPB), LDS_TOTAL, stream,
                           W, qidx, partials);
        hipLaunchKernelGGL(rap_reduce, dim3(Q_DIM / 8), dim3(256), 0, stream,
                           partials, outp);
    } else {
        (void)hipFuncSetAttribute((const void*)rap_main<true>,
                                  hipFuncAttributeMaxDynamicSharedMemorySize, LDS_TOTAL);
        (void)hipMemsetAsync(d_out, 0, Q_DIM * sizeof(float), stream);
        hipLaunchKernelGGL(rap_main<true>, dim3(NBLK), dim3(TPB), LDS_TOTAL, stream,
                           W, qidx, outp);
    }
}